// Round 4
// baseline (135.064 us; speedup 1.0000x reference)
//
#include <hip/hip_runtime.h>
#include <hip/hip_bf16.h>
#include <type_traits>
#include <utility>

// Fused 2-layer Elman RNN + FC, round 4: barrier-free wave-local.
// B=16384, T=28, IN=28, H1=128, H2=64, NC=10.
// 1024 blocks x 64 threads: ONE WAVE owns 16 batch rows end-to-end (all
// timesteps, all hidden columns, both layers, FC). No __syncthreads anywhere.
// All weight B-frags register-resident (~256 VGPR): wave computes D-frags,
// tanh, writes bf16 state to wave-private LDS, re-reads in A-frag layout
// (in-order LDS within a wave -> no barrier). A-frags reused twice (layer2
// of step t + layer1 recurrence of step t+1). FC slice t-1 MFMA'd inside
// the h1 write->read latency shadow. 1 wave/SIMD by construction
// (grid 1024 = 256 CU x 4 SIMDs).

#define NBLK 1024
#define NTHR 64

typedef float  f32x4 __attribute__((ext_vector_type(4)));
typedef short  s16x8 __attribute__((ext_vector_type(8)));
typedef __bf16 b16x8 __attribute__((ext_vector_type(8)));

template <typename V, typename = void> struct mfma_ok : std::false_type {};
template <typename V>
struct mfma_ok<V, std::void_t<decltype(__builtin_amdgcn_mfma_f32_16x16x32_bf16(
    std::declval<V>(), std::declval<V>(), std::declval<f32x4>(), 0, 0, 0))>>
    : std::true_type {};
using frag_t = std::conditional_t<mfma_ok<b16x8>::value, b16x8, s16x8>;

__device__ __forceinline__ f32x4 MFMA(frag_t a, frag_t b, f32x4 c) {
  return __builtin_amdgcn_mfma_f32_16x16x32_bf16(a, b, c, 0, 0, 0);
}

__device__ __forceinline__ unsigned short f2bf(float f) {
  unsigned int u = __float_as_uint(f);
  return (unsigned short)((u + 0x7FFFu + ((u >> 16) & 1u)) >> 16);  // RNE
}
__device__ __forceinline__ frag_t bitfrag(s16x8 s) {
  return __builtin_bit_cast(frag_t, s);
}
__device__ __forceinline__ frag_t pack8(float4 a, float4 b) {
  s16x8 r;
  r[0]=(short)f2bf(a.x); r[1]=(short)f2bf(a.y); r[2]=(short)f2bf(a.z); r[3]=(short)f2bf(a.w);
  r[4]=(short)f2bf(b.x); r[5]=(short)f2bf(b.y); r[6]=(short)f2bf(b.z); r[7]=(short)f2bf(b.w);
  return bitfrag(r);
}
__device__ __forceinline__ frag_t ldw8(const float* p) {
  float4 a = *(const float4*)(p);
  float4 b = *(const float4*)(p + 4);
  return pack8(a, b);
}
__device__ __forceinline__ frag_t ldw4z(const float* p) {  // 4 valid + 4 zero
  float4 a = *(const float4*)(p);
  return pack8(a, float4{0.f, 0.f, 0.f, 0.f});
}
__device__ __forceinline__ float tanh_fast(float v) {
  float e = __expf(2.0f * v);
  return 1.0f - 2.0f / (e + 1.0f);
}

__global__ __launch_bounds__(NTHR, 1)
void rnn_wave(const float* __restrict__ x,
              const float* __restrict__ W_ih1, const float* __restrict__ W_hh1,
              const float* __restrict__ b_ih1, const float* __restrict__ b_hh1,
              const float* __restrict__ W_ih2, const float* __restrict__ W_hh2,
              const float* __restrict__ b_ih2, const float* __restrict__ b_hh2,
              const float* __restrict__ W_fc,  const float* __restrict__ b_fc,
              float* __restrict__ out)
{
  // wave-private state relayout buffers: 4352 + 2304 = 6656 B/block
  __shared__ alignas(16) unsigned short h1s[16][136];
  __shared__ alignas(16) unsigned short h2s[16][72];

  const int tid = threadIdx.x;        // == lane, 0..63
  const int li  = tid & 15;           // A-row (batch) / D-col
  const int g   = tid >> 4;           // 0..3  k-group / D-row-group
  const int blk = blockIdx.x;
  // XOR-16 column swizzle: (row,col) stored at col ^ (((row>>3)&1)<<4)
  const int swr = ((li >> 3) & 1) << 4;     // reads:  row = li
  const int swv = ((g  >> 1) & 1) << 4;     // writes: row = g*4+r

  // ---- register-resident weight B-frags (bf16): 64 frags = 256 VGPR ----
  // frag (kt,nt): lane holds W[n][kt*32+g*8+e], n = nt*16+li
  frag_t wB1[4][8];                   // W_hh1: K=128, N=128
  #pragma unroll
  for (int kt = 0; kt < 4; ++kt)
    #pragma unroll
    for (int nt = 0; nt < 8; ++nt)
      wB1[kt][nt] = ldw8(W_hh1 + (nt * 16 + li) * 128 + kt * 32 + g * 8);
  frag_t wBi1[8];                     // W_ih1: K=28(pad32), N=128
  #pragma unroll
  for (int nt = 0; nt < 8; ++nt)
    wBi1[nt] = (g < 3) ? ldw8(W_ih1 + (nt * 16 + li) * 28 + g * 8)
                       : ldw4z(W_ih1 + (nt * 16 + li) * 28 + 24);
  frag_t wBi2[4][4];                  // W_ih2: K=128, N=64
  #pragma unroll
  for (int kt = 0; kt < 4; ++kt)
    #pragma unroll
    for (int nt = 0; nt < 4; ++nt)
      wBi2[kt][nt] = ldw8(W_ih2 + (nt * 16 + li) * 128 + kt * 32 + g * 8);
  frag_t wB2[2][4];                   // W_hh2: K=64, N=64
  #pragma unroll
  for (int kt = 0; kt < 2; ++kt)
    #pragma unroll
    for (int nt = 0; nt < 4; ++nt)
      wB2[kt][nt] = ldw8(W_hh2 + (nt * 16 + li) * 64 + kt * 32 + g * 8);

  float b1v[8], b2v[4];
  #pragma unroll
  for (int nt = 0; nt < 8; ++nt) { int n = nt * 16 + li; b1v[nt] = b_ih1[n] + b_hh1[n]; }
  #pragma unroll
  for (int nt = 0; nt < 4; ++nt) { int n = nt * 16 + li; b2v[nt] = b_ih2[n] + b_hh2[n]; }

  const float* xrow = x + (size_t)(blk * 16 + li) * 784 + g * 8;
  const int    cls  = (li < 10) ? li : 0;
  const float* wfp  = W_fc + (size_t)cls * 1792 + g * 8;

  frag_t h1A[4], h2A[2];              // A-frags of h1(t-1)/h2(t-1)
  f32x4  fca = {0.f, 0.f, 0.f, 0.f};

  float4 xa = *(const float4*)(xrow);
  float4 xb = (g < 3) ? *(const float4*)(xrow + 4) : float4{0.f, 0.f, 0.f, 0.f};

  #pragma unroll 1
  for (int t = 0; t < 28; ++t) {
    // x(t) frag; issue x(t+1) + W_fc(t-1) global loads early (consumed late)
    frag_t xA = pack8(xa, xb);
    if (t < 27) {
      xa = *(const float4*)(xrow + (t + 1) * 28);
      if (g < 3) xb = *(const float4*)(xrow + (t + 1) * 28 + 4);
    }
    float4 wfa0, wfb0, wfa1, wfb1;
    if (t > 0) {
      const float* wp = wfp + (t - 1) * 64;
      wfa0 = *(const float4*)(wp);       wfb0 = *(const float4*)(wp + 4);
      wfa1 = *(const float4*)(wp + 32);  wfb1 = *(const float4*)(wp + 36);
    }

    // ---- layer 1: pre1 = x W_ih1^T + h1(t-1) W_hh1^T + b ----
    f32x4 acc1[8];
    #pragma unroll
    for (int nt = 0; nt < 8; ++nt)
      acc1[nt] = f32x4{b1v[nt], b1v[nt], b1v[nt], b1v[nt]};
    #pragma unroll
    for (int nt = 0; nt < 8; ++nt)
      acc1[nt] = MFMA(xA, wBi1[nt], acc1[nt]);
    if (t > 0) {
      #pragma unroll
      for (int kt = 0; kt < 4; ++kt)
        #pragma unroll
        for (int nt = 0; nt < 8; ++nt)
          acc1[nt] = MFMA(h1A[kt], wB1[kt][nt], acc1[nt]);
    }

    // tanh -> bf16 -> wave-private LDS (D-layout rows g*4+r)
    #pragma unroll
    for (int nt = 0; nt < 8; ++nt) {
      const int colsw = ((nt * 16) ^ swv) + li;
      #pragma unroll
      for (int r = 0; r < 4; ++r)
        h1s[g * 4 + r][colsw] = f2bf(tanh_fast(acc1[nt][r]));
    }

    // FC for step t-1 (h2A = h2(t-1)) fills the h1 write->read shadow
    if (t > 0) {
      fca = MFMA(h2A[0], pack8(wfa0, wfb0), fca);
      fca = MFMA(h2A[1], pack8(wfa1, wfb1), fca);
    }

    // re-read h1(t) as A-frags (used by layer2 now AND layer1 at t+1)
    #pragma unroll
    for (int kt = 0; kt < 4; ++kt)
      h1A[kt] = *(const frag_t*)&h1s[li][(kt * 32 + g * 8) ^ swr];

    // ---- layer 2: pre2 = h1(t) W_ih2^T + h2(t-1) W_hh2^T + b ----
    f32x4 acc2[4];
    #pragma unroll
    for (int nt = 0; nt < 4; ++nt)
      acc2[nt] = f32x4{b2v[nt], b2v[nt], b2v[nt], b2v[nt]};
    #pragma unroll
    for (int kt = 0; kt < 4; ++kt)
      #pragma unroll
      for (int nt = 0; nt < 4; ++nt)
        acc2[nt] = MFMA(h1A[kt], wBi2[kt][nt], acc2[nt]);
    if (t > 0) {
      #pragma unroll
      for (int kt = 0; kt < 2; ++kt)
        #pragma unroll
        for (int nt = 0; nt < 4; ++nt)
          acc2[nt] = MFMA(h2A[kt], wB2[kt][nt], acc2[nt]);
    }

    #pragma unroll
    for (int nt = 0; nt < 4; ++nt) {
      const int colsw = ((nt * 16) ^ swv) + li;
      #pragma unroll
      for (int r = 0; r < 4; ++r)
        h2s[g * 4 + r][colsw] = f2bf(tanh_fast(acc2[nt][r]));
    }

    // re-read h2(t) as A-frags (used by FC + layer2 recurrence at t+1)
    #pragma unroll
    for (int kt = 0; kt < 2; ++kt)
      h2A[kt] = *(const frag_t*)&h2s[li][(kt * 32 + g * 8) ^ swr];
  }

  // ---- final FC slice (t=27) + store ----
  {
    const float* wp = wfp + 27 * 64;
    fca = MFMA(h2A[0], ldw8(wp), fca);
    fca = MFMA(h2A[1], ldw8(wp + 32), fca);
  }
  if (li < 10) {
    const float bv = b_fc[li];
    #pragma unroll
    for (int r = 0; r < 4; ++r)
      out[(size_t)(blk * 16 + g * 4 + r) * 10 + li] = fca[r] + bv;
  }
}

extern "C" void kernel_launch(void* const* d_in, const int* in_sizes, int n_in,
                              void* d_out, int out_size, void* d_ws, size_t ws_size,
                              hipStream_t stream) {
  const float* x     = (const float*)d_in[0];
  const float* W_ih1 = (const float*)d_in[1];
  const float* W_hh1 = (const float*)d_in[2];
  const float* b_ih1 = (const float*)d_in[3];
  const float* b_hh1 = (const float*)d_in[4];
  const float* W_ih2 = (const float*)d_in[5];
  const float* W_hh2 = (const float*)d_in[6];
  const float* b_ih2 = (const float*)d_in[7];
  const float* b_hh2 = (const float*)d_in[8];
  const float* W_fc  = (const float*)d_in[9];
  const float* b_fc  = (const float*)d_in[10];

  rnn_wave<<<NBLK, NTHR, 0, stream>>>(x, W_ih1, W_hh1, b_ih1, b_hh1,
                                      W_ih2, W_hh2, b_ih2, b_hh2,
                                      W_fc, b_fc, (float*)d_out);
}

// Round 5
// 112.407 us; speedup vs baseline: 1.2016x; 1.2016x over previous
//
#include <hip/hip_runtime.h>
#include <hip/hip_bf16.h>
#include <type_traits>
#include <utility>

// Fused 2-layer Elman RNN + FC, round 5: round-3 chassis + VALU diet.
// B=16384, T=28, IN=28, H1=128, H2=64, NC=10.
// 1024 blocks x 256 thr; block owns 16 batch rows; waves N-split-4.
// NEW vs round 3:
//  - pre-pass kernel converts all weights to bf16 into d_ws (W_ih1 padded
//    K=32); main loop loads B-frags as raw 16B loads (no per-step cvt VALU)
//  - native __bf16 casts (v_cvt_pk_bf16_f32) replace software RNE bit-twiddle
//  - ONE barrier per step (was 2): FC(t-1) deferred into post-barrier phase,
//    sharing the h2A frags read for layer-2's recurrence
//  - h1A frags read once per step (post-barrier), feed layer 2 only;
//    layer-1 recurrence re-reads pb buffer pre-barrier (synced by B1(t-1))

#define NBLK 1024
#define NTHR 256

typedef float  f32x4 __attribute__((ext_vector_type(4)));
typedef short  s16x8 __attribute__((ext_vector_type(8)));
typedef __bf16 b16x8 __attribute__((ext_vector_type(8)));

template <typename V, typename = void> struct mfma_ok : std::false_type {};
template <typename V>
struct mfma_ok<V, std::void_t<decltype(__builtin_amdgcn_mfma_f32_16x16x32_bf16(
    std::declval<V>(), std::declval<V>(), std::declval<f32x4>(), 0, 0, 0))>>
    : std::true_type {};
using frag_t = std::conditional_t<mfma_ok<b16x8>::value, b16x8, s16x8>;

__device__ __forceinline__ f32x4 MFMA(frag_t a, frag_t b, f32x4 c) {
  return __builtin_amdgcn_mfma_f32_16x16x32_bf16(a, b, c, 0, 0, 0);
}

__device__ __forceinline__ unsigned short f2bf_n(float f) {  // native cvt (RNE)
  __bf16 h = (__bf16)f;
  return __builtin_bit_cast(unsigned short, h);
}
__device__ __forceinline__ frag_t packx(float4 a, float4 b) {
  s16x8 r;
  r[0]=(short)f2bf_n(a.x); r[1]=(short)f2bf_n(a.y); r[2]=(short)f2bf_n(a.z); r[3]=(short)f2bf_n(a.w);
  r[4]=(short)f2bf_n(b.x); r[5]=(short)f2bf_n(b.y); r[6]=(short)f2bf_n(b.z); r[7]=(short)f2bf_n(b.w);
  return __builtin_bit_cast(frag_t, r);
}
__device__ __forceinline__ float tanh_fast(float v) {
  float e = __expf(2.0f * v);
  return 1.0f - 2.0f / (e + 1.0f);
}

// ---- bf16 weight cache layout in d_ws (u16 elements) ----
#define OFF_WIH1 0        // [128][32]  (K padded 28->32 with zeros)
#define OFF_WHH1 4096     // [128][128]
#define OFF_WIH2 20480    // [64][128]
#define OFF_WHH2 28672    // [64][64]
#define OFF_WFC  32768    // [10][1792]
#define WS_U16   50688

__global__ void cvt_weights(const float* __restrict__ wih1, const float* __restrict__ whh1,
                            const float* __restrict__ wih2, const float* __restrict__ whh2,
                            const float* __restrict__ wfc,  unsigned short* __restrict__ ws)
{
  int i = blockIdx.x * 256 + threadIdx.x;
  if (i < 4096) {                       // W_ih1 padded
    int r = i >> 5, c = i & 31;
    ws[OFF_WIH1 + i] = (c < 28) ? f2bf_n(wih1[r * 28 + c]) : (unsigned short)0;
    return;
  }
  i -= 4096;
  if (i < 16384) { ws[OFF_WHH1 + i] = f2bf_n(whh1[i]); return; }
  i -= 16384;
  if (i < 8192)  { ws[OFF_WIH2 + i] = f2bf_n(wih2[i]); return; }
  i -= 8192;
  if (i < 4096)  { ws[OFF_WHH2 + i] = f2bf_n(whh2[i]); return; }
  i -= 4096;
  if (i < 17920) { ws[OFF_WFC + i] = f2bf_n(wfc[i]); return; }
}

__global__ __launch_bounds__(NTHR, 4)
void rnn_mfma5(const float* __restrict__ x,
               const unsigned short* __restrict__ ws,
               const float* __restrict__ b_ih1, const float* __restrict__ b_hh1,
               const float* __restrict__ b_ih2, const float* __restrict__ b_hh2,
               const float* __restrict__ b_fc,
               float* __restrict__ out)
{
  // LDS: 8704 + 4608 + 2048 = 15,360 B -> 4 blocks/CU
  __shared__ alignas(16) unsigned short h1s[2][16][136];
  __shared__ alignas(16) unsigned short h2s[2][16][72];
  __shared__ alignas(16) float red[2][16][16];

  const int tid  = threadIdx.x;
  const int wn   = tid >> 6;          // wave = N-split index 0..3
  const int lane = tid & 63;
  const int li   = lane & 15;         // A-row (batch) / D-col
  const int g    = lane >> 4;         // 0..3 k-group / D-row-group
  const int blk  = blockIdx.x;
  // XOR-16 column swizzle: (row,col) stored at col ^ (((row>>3)&1)<<4)
  const int swr  = ((li >> 3) & 1) << 4;          // reads:  row = li
  const int swv  = ((g  >> 1) & 1) << 4;          // writes: row = g*4+r

  // ---- register-resident weight B-frags: raw bf16 16B loads ----
  const int n1 = wn * 32 + li;        // (+nt*16)
  const int n2 = wn * 16 + li;
  frag_t wB1[4][2], wBi1[2], wBi2[4], wB2[2];
  #pragma unroll
  for (int kt = 0; kt < 4; ++kt)
    #pragma unroll
    for (int nt = 0; nt < 2; ++nt)
      wB1[kt][nt] = *(const frag_t*)(ws + OFF_WHH1 + (n1 + nt * 16) * 128 + kt * 32 + g * 8);
  #pragma unroll
  for (int nt = 0; nt < 2; ++nt)
    wBi1[nt] = *(const frag_t*)(ws + OFF_WIH1 + (n1 + nt * 16) * 32 + g * 8);
  #pragma unroll
  for (int kt = 0; kt < 4; ++kt)
    wBi2[kt] = *(const frag_t*)(ws + OFF_WIH2 + n2 * 128 + kt * 32 + g * 8);
  #pragma unroll
  for (int kt = 0; kt < 2; ++kt)
    wB2[kt] = *(const frag_t*)(ws + OFF_WHH2 + n2 * 64 + kt * 32 + g * 8);

  float b1v[2];
  b1v[0] = b_ih1[n1] + b_hh1[n1];
  b1v[1] = b_ih1[n1 + 16] + b_hh1[n1 + 16];
  const float b2v = b_ih2[n2] + b_hh2[n2];

  const float* xrow = x + (size_t)(blk * 16 + li) * 784 + g * 8;
  const int    cls  = (li < 10) ? li : 0;
  const unsigned short* wfp = ws + OFF_WFC + cls * 1792 + g * 8;

  f32x4 fca = {0.f, 0.f, 0.f, 0.f};

  #pragma unroll 1
  for (int t = 0; t < 28; ++t) {
    const int cb = t & 1, pb = cb ^ 1;

    // ================= P1: layer 1 =================
    float4 xa = *(const float4*)(xrow + t * 28);
    float4 xb = float4{0.f, 0.f, 0.f, 0.f};
    if (g < 3) xb = *(const float4*)(xrow + t * 28 + 4);

    f32x4 acc1[2];
    acc1[0] = f32x4{b1v[0], b1v[0], b1v[0], b1v[0]};
    acc1[1] = f32x4{b1v[1], b1v[1], b1v[1], b1v[1]};

    if (t > 0) {                       // h1s[pb] synced by B1(t-1)
      #pragma unroll
      for (int kt = 0; kt < 4; ++kt) {
        frag_t a = *(const frag_t*)&h1s[pb][li][(kt * 32 + g * 8) ^ swr];
        acc1[0] = MFMA(a, wB1[kt][0], acc1[0]);
        acc1[1] = MFMA(a, wB1[kt][1], acc1[1]);
      }
    }
    {
      frag_t xA = packx(xa, xb);
      acc1[0] = MFMA(xA, wBi1[0], acc1[0]);
      acc1[1] = MFMA(xA, wBi1[1], acc1[1]);
    }

    #pragma unroll
    for (int nt = 0; nt < 2; ++nt) {
      const int colsw = ((wn * 32 + nt * 16) ^ swv) + li;
      #pragma unroll
      for (int r = 0; r < 4; ++r)
        h1s[cb][g * 4 + r][colsw] = f2bf_n(tanh_fast(acc1[nt][r]));
    }

    __syncthreads();   // B1(t): h1(t) visible; also syncs h2(t-1) writes

    // ================= P2: layer 2 + FC(t-1) =================
    frag_t h1A[4];
    #pragma unroll
    for (int kt = 0; kt < 4; ++kt)
      h1A[kt] = *(const frag_t*)&h1s[cb][li][(kt * 32 + g * 8) ^ swr];

    f32x4 acc2 = f32x4{b2v, b2v, b2v, b2v};
    #pragma unroll
    for (int kt = 0; kt < 4; ++kt)
      acc2 = MFMA(h1A[kt], wBi2[kt], acc2);

    if (t > 0) {
      frag_t h2A[2];
      #pragma unroll
      for (int kt = 0; kt < 2; ++kt)
        h2A[kt] = *(const frag_t*)&h2s[pb][li][(kt * 32 + g * 8) ^ swr];
      #pragma unroll
      for (int kt = 0; kt < 2; ++kt)
        acc2 = MFMA(h2A[kt], wB2[kt], acc2);
      // FC for step t-1 (reuses h2A[wn])
      if (wn < 2) {
        frag_t bfc = *(const frag_t*)(wfp + (t - 1) * 64 + wn * 32);
        fca = MFMA(h2A[wn], bfc, fca);
      }
    }

    {
      const int colsw = ((wn * 16) ^ swv) + li;
      #pragma unroll
      for (int r = 0; r < 4; ++r)
        h2s[cb][g * 4 + r][colsw] = f2bf_n(tanh_fast(acc2[r]));
    }
    // no second barrier: h2s[cb] reads happen after B1(t+1)
  }

  // ---- epilogue: FC(27), 2-way K-reduce, bias, store ----
  __syncthreads();                     // h2(27) = h2s[1] visible
  if (wn < 2) {
    frag_t a   = *(const frag_t*)&h2s[1][li][(wn * 32 + g * 8) ^ swr];
    frag_t bfc = *(const frag_t*)(wfp + 27 * 64 + wn * 32);
    fca = MFMA(a, bfc, fca);
    #pragma unroll
    for (int r = 0; r < 4; ++r)
      red[wn][g * 4 + r][li] = fca[r];
  }
  __syncthreads();
  if (tid < 160) {
    const int b = tid / 10, c = tid - b * 10;
    out[(size_t)(blk * 16 + b) * 10 + c] = red[0][b][c] + red[1][b][c] + b_fc[c];
  }
}

extern "C" void kernel_launch(void* const* d_in, const int* in_sizes, int n_in,
                              void* d_out, int out_size, void* d_ws, size_t ws_size,
                              hipStream_t stream) {
  const float* x     = (const float*)d_in[0];
  const float* W_ih1 = (const float*)d_in[1];
  const float* W_hh1 = (const float*)d_in[2];
  const float* b_ih1 = (const float*)d_in[3];
  const float* b_hh1 = (const float*)d_in[4];
  const float* W_ih2 = (const float*)d_in[5];
  const float* W_hh2 = (const float*)d_in[6];
  const float* b_ih2 = (const float*)d_in[7];
  const float* b_hh2 = (const float*)d_in[8];
  const float* W_fc  = (const float*)d_in[9];
  const float* b_fc  = (const float*)d_in[10];
  unsigned short* ws = (unsigned short*)d_ws;

  cvt_weights<<<(WS_U16 + 255) / 256, 256, 0, stream>>>(W_ih1, W_hh1, W_ih2, W_hh2, W_fc, ws);
  rnn_mfma5<<<NBLK, NTHR, 0, stream>>>(x, ws, b_ih1, b_hh1, b_ih2, b_hh2, b_fc,
                                       (float*)d_out);
}

// Round 6
// 84.776 us; speedup vs baseline: 1.5932x; 1.3259x over previous
//
#include <hip/hip_runtime.h>
#include <hip/hip_bf16.h>
#include <type_traits>
#include <utility>

// Fused 2-layer Elman RNN + FC, round 6: R3 chassis, register-resident weights.
// B=16384, T=28, IN=28, H1=128, H2=64, NC=10.
// 1024 blocks x 256 thr; block owns 16 batch rows; waves N-split-4;
// 2 barriers/step (R3 structure — measured best).
// Single mechanism change vs R3: __launch_bounds__(256,2) -> VGPR cap 256 so
// the 16 weight B-frags (64 VGPR) stay register-resident instead of spilling
// to scratch (R3/R5 showed VGPR=64 + 15-40MB scratch WRITE_SIZE).
// Carried from R5 (harmless, VALU-reducing): weights pre-converted to bf16
// in d_ws by a prepass kernel; native __bf16 casts.

#define NBLK 1024
#define NTHR 256

typedef float  f32x4 __attribute__((ext_vector_type(4)));
typedef short  s16x8 __attribute__((ext_vector_type(8)));
typedef __bf16 b16x8 __attribute__((ext_vector_type(8)));

template <typename V, typename = void> struct mfma_ok : std::false_type {};
template <typename V>
struct mfma_ok<V, std::void_t<decltype(__builtin_amdgcn_mfma_f32_16x16x32_bf16(
    std::declval<V>(), std::declval<V>(), std::declval<f32x4>(), 0, 0, 0))>>
    : std::true_type {};
using frag_t = std::conditional_t<mfma_ok<b16x8>::value, b16x8, s16x8>;

__device__ __forceinline__ f32x4 MFMA(frag_t a, frag_t b, f32x4 c) {
  return __builtin_amdgcn_mfma_f32_16x16x32_bf16(a, b, c, 0, 0, 0);
}

__device__ __forceinline__ unsigned short f2bf_n(float f) {  // native cvt (RNE)
  __bf16 h = (__bf16)f;
  return __builtin_bit_cast(unsigned short, h);
}
__device__ __forceinline__ frag_t packx(float4 a, float4 b) {
  s16x8 r;
  r[0]=(short)f2bf_n(a.x); r[1]=(short)f2bf_n(a.y); r[2]=(short)f2bf_n(a.z); r[3]=(short)f2bf_n(a.w);
  r[4]=(short)f2bf_n(b.x); r[5]=(short)f2bf_n(b.y); r[6]=(short)f2bf_n(b.z); r[7]=(short)f2bf_n(b.w);
  return __builtin_bit_cast(frag_t, r);
}
__device__ __forceinline__ float tanh_fast(float v) {
  float e = __expf(2.0f * v);
  return 1.0f - 2.0f / (e + 1.0f);
}

// ---- bf16 weight cache layout in d_ws (u16 elements) ----
#define OFF_WIH1 0        // [128][32]  (K padded 28->32 with zeros)
#define OFF_WHH1 4096     // [128][128]
#define OFF_WIH2 20480    // [64][128]
#define OFF_WHH2 28672    // [64][64]
#define OFF_WFC  32768    // [10][1792]
#define WS_U16   50688

__global__ void cvt_weights(const float* __restrict__ wih1, const float* __restrict__ whh1,
                            const float* __restrict__ wih2, const float* __restrict__ whh2,
                            const float* __restrict__ wfc,  unsigned short* __restrict__ ws)
{
  int i = blockIdx.x * 256 + threadIdx.x;
  if (i < 4096) {                       // W_ih1 padded
    int r = i >> 5, c = i & 31;
    ws[OFF_WIH1 + i] = (c < 28) ? f2bf_n(wih1[r * 28 + c]) : (unsigned short)0;
    return;
  }
  i -= 4096;
  if (i < 16384) { ws[OFF_WHH1 + i] = f2bf_n(whh1[i]); return; }
  i -= 16384;
  if (i < 8192)  { ws[OFF_WIH2 + i] = f2bf_n(wih2[i]); return; }
  i -= 8192;
  if (i < 4096)  { ws[OFF_WHH2 + i] = f2bf_n(whh2[i]); return; }
  i -= 4096;
  if (i < 17920) { ws[OFF_WFC + i] = f2bf_n(wfc[i]); return; }
}

__global__ __launch_bounds__(NTHR, 2)
void rnn_mfma6(const float* __restrict__ x,
               const unsigned short* __restrict__ ws,
               const float* __restrict__ b_ih1, const float* __restrict__ b_hh1,
               const float* __restrict__ b_ih2, const float* __restrict__ b_hh2,
               const float* __restrict__ b_fc,
               float* __restrict__ out)
{
  // LDS: 8704 + 4608 + 2048 = 15,360 B
  __shared__ alignas(16) unsigned short h1s[2][16][136];
  __shared__ alignas(16) unsigned short h2s[2][16][72];
  __shared__ alignas(16) float red[2][16][16];

  const int tid  = threadIdx.x;
  const int wn   = tid >> 6;          // wave = N-split index 0..3
  const int lane = tid & 63;
  const int li   = lane & 15;         // A-row (batch) / D-col
  const int g    = lane >> 4;         // 0..3 k-group / D-row-group
  const int blk  = blockIdx.x;
  // XOR-16 column swizzle: (row,col) stored at col ^ (((row>>3)&1)<<4)
  const int swr  = ((li >> 3) & 1) << 4;          // reads:  row = li
  const int swv  = ((g  >> 1) & 1) << 4;          // writes: row = g*4+r

  // ---- register-resident weight B-frags: raw bf16 16B loads, LIVE all loop ----
  const int n1 = wn * 32 + li;        // (+nt*16)
  const int n2 = wn * 16 + li;
  frag_t wB1[4][2], wBi1[2], wBi2[4], wB2[2];
  #pragma unroll
  for (int kt = 0; kt < 4; ++kt)
    #pragma unroll
    for (int nt = 0; nt < 2; ++nt)
      wB1[kt][nt] = *(const frag_t*)(ws + OFF_WHH1 + (n1 + nt * 16) * 128 + kt * 32 + g * 8);
  #pragma unroll
  for (int nt = 0; nt < 2; ++nt)
    wBi1[nt] = *(const frag_t*)(ws + OFF_WIH1 + (n1 + nt * 16) * 32 + g * 8);
  #pragma unroll
  for (int kt = 0; kt < 4; ++kt)
    wBi2[kt] = *(const frag_t*)(ws + OFF_WIH2 + n2 * 128 + kt * 32 + g * 8);
  #pragma unroll
  for (int kt = 0; kt < 2; ++kt)
    wB2[kt] = *(const frag_t*)(ws + OFF_WHH2 + n2 * 64 + kt * 32 + g * 8);

  float b1v[2];
  b1v[0] = b_ih1[n1] + b_hh1[n1];
  b1v[1] = b_ih1[n1 + 16] + b_hh1[n1 + 16];
  const float b2v = b_ih2[n2] + b_hh2[n2];

  const float* xrow = x + (size_t)(blk * 16 + li) * 784 + g * 8;
  const int    cls  = (li < 10) ? li : 0;
  const unsigned short* wfp = ws + OFF_WFC + cls * 1792 + (wn & 1) * 32 + g * 8;

  f32x4 fca = {0.f, 0.f, 0.f, 0.f};

  #pragma unroll 1
  for (int t = 0; t < 28; ++t) {
    const int cb = t & 1, pb = cb ^ 1;

    // ---- layer 1 ----
    float4 xa = *(const float4*)(xrow + t * 28);
    float4 xb = float4{0.f, 0.f, 0.f, 0.f};
    if (g < 3) xb = *(const float4*)(xrow + t * 28 + 4);

    f32x4 acc1[2];
    acc1[0] = f32x4{b1v[0], b1v[0], b1v[0], b1v[0]};
    acc1[1] = f32x4{b1v[1], b1v[1], b1v[1], b1v[1]};

    if (t > 0) {
      #pragma unroll
      for (int kt = 0; kt < 4; ++kt) {
        frag_t a = *(const frag_t*)&h1s[pb][li][(kt * 32 + g * 8) ^ swr];
        acc1[0] = MFMA(a, wB1[kt][0], acc1[0]);
        acc1[1] = MFMA(a, wB1[kt][1], acc1[1]);
      }
    }
    {
      frag_t xA = packx(xa, xb);
      acc1[0] = MFMA(xA, wBi1[0], acc1[0]);
      acc1[1] = MFMA(xA, wBi1[1], acc1[1]);
    }

    #pragma unroll
    for (int nt = 0; nt < 2; ++nt) {
      const int colsw = ((wn * 32 + nt * 16) ^ swv) + li;
      #pragma unroll
      for (int r = 0; r < 4; ++r)
        h1s[cb][g * 4 + r][colsw] = f2bf_n(tanh_fast(acc1[nt][r]));
    }

    __syncthreads();   // B1: h1(t) visible

    // ---- layer 2 ----
    f32x4 acc2 = f32x4{b2v, b2v, b2v, b2v};
    #pragma unroll
    for (int kt = 0; kt < 4; ++kt) {
      frag_t a = *(const frag_t*)&h1s[cb][li][(kt * 32 + g * 8) ^ swr];
      acc2 = MFMA(a, wBi2[kt], acc2);
    }
    if (t > 0) {
      #pragma unroll
      for (int kt = 0; kt < 2; ++kt) {
        frag_t a = *(const frag_t*)&h2s[pb][li][(kt * 32 + g * 8) ^ swr];
        acc2 = MFMA(a, wB2[kt], acc2);
      }
    }
    {
      const int colsw = ((wn * 16) ^ swv) + li;
      #pragma unroll
      for (int r = 0; r < 4; ++r)
        h2s[cb][g * 4 + r][colsw] = f2bf_n(tanh_fast(acc2[r]));
    }

    __syncthreads();   // B2: h2(t) visible

    // ---- FC accumulation (waves 0,1 split K=64) ----
    if (wn < 2) {
      frag_t a   = *(const frag_t*)&h2s[cb][li][(wn * 32 + g * 8) ^ swr];
      frag_t bfc = *(const frag_t*)(wfp + t * 64);
      fca = MFMA(a, bfc, fca);
    }
  }

  // ---- epilogue: 2-way K-reduce + bias + store ----
  if (wn < 2) {
    #pragma unroll
    for (int r = 0; r < 4; ++r)
      red[wn][g * 4 + r][li] = fca[r];
  }
  __syncthreads();
  if (tid < 160) {
    const int b = tid / 10, c = tid - b * 10;
    out[(size_t)(blk * 16 + b) * 10 + c] = red[0][b][c] + red[1][b][c] + b_fc[c];
  }
}

extern "C" void kernel_launch(void* const* d_in, const int* in_sizes, int n_in,
                              void* d_out, int out_size, void* d_ws, size_t ws_size,
                              hipStream_t stream) {
  const float* x     = (const float*)d_in[0];
  const float* W_ih1 = (const float*)d_in[1];
  const float* W_hh1 = (const float*)d_in[2];
  const float* b_ih1 = (const float*)d_in[3];
  const float* b_hh1 = (const float*)d_in[4];
  const float* W_ih2 = (const float*)d_in[5];
  const float* W_hh2 = (const float*)d_in[6];
  const float* b_ih2 = (const float*)d_in[7];
  const float* b_hh2 = (const float*)d_in[8];
  const float* W_fc  = (const float*)d_in[9];
  const float* b_fc  = (const float*)d_in[10];
  unsigned short* ws = (unsigned short*)d_ws;

  cvt_weights<<<(WS_U16 + 255) / 256, 256, 0, stream>>>(W_ih1, W_hh1, W_ih2, W_hh2, W_fc, ws);
  rnn_mfma6<<<NBLK, NTHR, 0, stream>>>(x, ws, b_ih1, b_hh1, b_ih2, b_hh2, b_fc,
                                       (float*)d_out);
}